// Round 9
// baseline (136.957 us; speedup 1.0000x reference)
//
#include <hip/hip_runtime.h>
#include <hip/hip_bf16.h>

// MXFP8Linear: out[n,j] = sum_b sx[n,b]*sw[j,b]*dot32(fp8(x),fp8(w)) + bias[j]
// R8/R9: stage fp8+scales (halves L3 panel traffic 384->230MB), dequant to
// bf16 in-register right before MFMA. Numerically identical to bf16-staging
// rounds (same cvt_f32_fp8*scale->bf16 values reach the MFMA).
// fp8 k-order is permuted per 64-group so one ds_read_b128 per fragment row
// yields [kk0 j0..7 | kk1 j0..7] (both K-halves, dense banks, no swizzle).
// R9 fix: fp8->f32 conversion needs LITERAL byte selectors (hand-unrolled,
// packed cvt_pk_f32_fp8 where available).

typedef __attribute__((ext_vector_type(8))) __bf16 bf16x8;
typedef __attribute__((ext_vector_type(4))) float f32x4;
typedef __attribute__((ext_vector_type(2))) float f32x2;

#define NMAT 2048
#define FP8_MAX 448.0f

__device__ inline __bf16 tobf(float f) {
  union { __hip_bfloat16 h; __bf16 b; } cv;
  cv.h = __float2bfloat16(f);
  return cv.b;
}

// Coalesced qdq -> fp8 (permuted k) + per-32-block f32 scales.
// perm: pos = (k&~63) | ((k>>3&3)<<4) | ((k>>5&1)<<3) | (k&7)
__global__ __launch_bounds__(256) void qdq_kernel(const float* __restrict__ x,
                                                  unsigned char* __restrict__ xq,
                                                  float* __restrict__ xs,
                                                  const float* __restrict__ w,
                                                  unsigned char* __restrict__ wq,
                                                  float* __restrict__ wss) {
  int g = blockIdx.x;
  const float* in; unsigned char* oq; float* os;
  if (g >= 4096) { in = w; oq = wq; os = wss; g -= 4096; }
  else           { in = x; oq = xq; os = xs; }
  const int t = threadIdx.x;
  const size_t base = (size_t)g * 1024;  // floats per workgroup
  float4 v = ((const float4*)(in + base))[t];
  float amax = fmaxf(fmaxf(fabsf(v.x), fabsf(v.y)), fmaxf(fabsf(v.z), fabsf(v.w)));
  amax = fmaxf(amax, __shfl_xor(amax, 1));
  amax = fmaxf(amax, __shfl_xor(amax, 2));
  amax = fmaxf(amax, __shfl_xor(amax, 4));
  float s = fmaxf(amax / FP8_MAX, 1e-30f);  // real div to match reference
  int p = __builtin_amdgcn_cvt_pk_fp8_f32(v.x / s, v.y / s, 0, false);
  p = __builtin_amdgcn_cvt_pk_fp8_f32(v.z / s, v.w / s, p, true);
  const int idx = (int)base + t * 4;       // element index
  const int row = idx >> 11;
  const int k = idx & 2047;
  const int pb = (k & ~63) | (((k >> 3) & 3) << 4) | (((k >> 5) & 1) << 3) | (k & 7);
  *(unsigned*)(oq + (size_t)row * 2048 + pb) = (unsigned)p;
  if ((t & 7) == 0) os[row * 64 + (k >> 5)] = s;
}

// 16 fp8 bytes [w0|w1] (one kk half), scale s -> bf16x8.
// Identical math to bf16-staging rounds: cvt is HW fp8->f32, then *s, ->bf16.
__device__ inline bf16x8 dq8(unsigned w0, unsigned w1, float s) {
  bf16x8 r;
#if __has_builtin(__builtin_amdgcn_cvt_pk_f32_fp8)
  f32x2 p01 = __builtin_amdgcn_cvt_pk_f32_fp8((int)w0, false);
  f32x2 p23 = __builtin_amdgcn_cvt_pk_f32_fp8((int)w0, true);
  f32x2 p45 = __builtin_amdgcn_cvt_pk_f32_fp8((int)w1, false);
  f32x2 p67 = __builtin_amdgcn_cvt_pk_f32_fp8((int)w1, true);
  r[0] = tobf(p01[0] * s); r[1] = tobf(p01[1] * s);
  r[2] = tobf(p23[0] * s); r[3] = tobf(p23[1] * s);
  r[4] = tobf(p45[0] * s); r[5] = tobf(p45[1] * s);
  r[6] = tobf(p67[0] * s); r[7] = tobf(p67[1] * s);
#else
  r[0] = tobf(__builtin_amdgcn_cvt_f32_fp8((int)w0, 0) * s);
  r[1] = tobf(__builtin_amdgcn_cvt_f32_fp8((int)w0, 1) * s);
  r[2] = tobf(__builtin_amdgcn_cvt_f32_fp8((int)w0, 2) * s);
  r[3] = tobf(__builtin_amdgcn_cvt_f32_fp8((int)w0, 3) * s);
  r[4] = tobf(__builtin_amdgcn_cvt_f32_fp8((int)w1, 0) * s);
  r[5] = tobf(__builtin_amdgcn_cvt_f32_fp8((int)w1, 1) * s);
  r[6] = tobf(__builtin_amdgcn_cvt_f32_fp8((int)w1, 2) * s);
  r[7] = tobf(__builtin_amdgcn_cvt_f32_fp8((int)w1, 3) * s);
#endif
  return r;
}

// C[n,j] = sum_k A[n,k]*B[j,k] + bias[j]
// BM=128 BN=64 BK=64, 256 thr (4 waves 2Mx2N, wave tile 64x32).
// LDS buf: A fp8 8K | B fp8 4K | As [128][2] f32 1K | Bs [64][2](+dup) 1K
//  = 14336 B; double-buffered = 28672 B. grid 512 = 2 blocks/CU.
// Loop: STAGE(next: 5 loads); vmcnt(5); s_barrier; compute(cur); s_barrier.
__global__ __launch_bounds__(256) void gemm_kernel(const unsigned char* __restrict__ Aq,
                                                   const float* __restrict__ As,
                                                   const unsigned char* __restrict__ Bq,
                                                   const float* __restrict__ Bs,
                                                   const float* __restrict__ bias,
                                                   float* __restrict__ C) {
  __shared__ __align__(16) char lds[28672];
  const int tid  = threadIdx.x;
  const int lane = tid & 63;
  const int wid  = tid >> 6;
  const int wr   = wid >> 1;   // 0..1 -> row offset wr*64
  const int wc   = wid & 1;    // 0..1 -> col offset wc*32

  // 2D-chunked XCD mapping (kept from R7; harmless if dispatch differs)
  const int bid = blockIdx.x;
  const int xcd = bid & 7;
  const int k8  = bid >> 3;
  const int row0 = ((xcd >> 2) * 8 + (k8 >> 3)) * 128;
  const int col0 = ((xcd & 3) * 8 + (k8 & 7)) * 64;

  // staging source bases (kt-invariant parts)
  const unsigned char* AgD0 = Aq + (size_t)(row0 + (tid >> 2)) * 2048 + (tid & 3) * 16;
  const unsigned char* AgD1 = Aq + (size_t)(row0 + 64 + (tid >> 2)) * 2048 + (tid & 3) * 16;
  const unsigned char* BgD  = Bq + (size_t)(col0 + (tid >> 2)) * 2048 + (tid & 3) * 16;
  const float* AgS = As + (size_t)(row0 + (tid >> 1)) * 64 + (tid & 1);
  const float* BgS = Bs + (size_t)(col0 + ((tid & 127) >> 1)) * 64 + (tid & 1);
  const int dst16 = tid * 16;
  const int dst4  = tid * 4;

#define STAGE(buf, kt) do {                                                      \
    char* lb = lds + (buf) * 14336;                                              \
    __builtin_amdgcn_global_load_lds(                                            \
        (const __attribute__((address_space(1))) unsigned*)(AgD0 + (kt) * 64),   \
        (__attribute__((address_space(3))) unsigned*)(lb + dst16), 16, 0, 0);    \
    __builtin_amdgcn_global_load_lds(                                            \
        (const __attribute__((address_space(1))) unsigned*)(AgD1 + (kt) * 64),   \
        (__attribute__((address_space(3))) unsigned*)(lb + 4096 + dst16), 16, 0, 0); \
    __builtin_amdgcn_global_load_lds(                                            \
        (const __attribute__((address_space(1))) unsigned*)(BgD + (kt) * 64),    \
        (__attribute__((address_space(3))) unsigned*)(lb + 8192 + dst16), 16, 0, 0); \
    __builtin_amdgcn_global_load_lds(                                            \
        (const __attribute__((address_space(1))) unsigned*)(AgS + (kt) * 2),     \
        (__attribute__((address_space(3))) unsigned*)(lb + 12288 + dst4), 4, 0, 0);  \
    __builtin_amdgcn_global_load_lds(                                            \
        (const __attribute__((address_space(1))) unsigned*)(BgS + (kt) * 2),     \
        (__attribute__((address_space(3))) unsigned*)(lb + 13312 + dst4), 4, 0, 0);  \
  } while (0)

#define WAIT5_BAR() do {                                   \
    asm volatile("s_waitcnt vmcnt(5)" ::: "memory");       \
    __builtin_amdgcn_sched_barrier(0);                     \
    __builtin_amdgcn_s_barrier();                          \
  } while (0)
#define POST_BAR() do {                                    \
    __builtin_amdgcn_sched_barrier(0);                     \
    __builtin_amdgcn_s_barrier();                          \
  } while (0)

  const int l15 = lane & 15;
  const int lq  = (lane >> 4) * 16;  // 16B chunk within 64B fp8 row

  f32x4 acc[4][2] = {};

  auto compute = [&](const int buf) {
    const char* lb = lds + buf * 14336;
    uint4 araw[4]; f32x2 ascl[4];
    uint4 braw[2]; f32x2 bscl[2];
#pragma unroll
    for (int m = 0; m < 4; ++m) {
      const int r = wr * 64 + m * 16 + l15;
      araw[m] = *(const uint4*)(lb + r * 64 + lq);
      ascl[m] = *(const f32x2*)(lb + 12288 + r * 8);
    }
#pragma unroll
    for (int n = 0; n < 2; ++n) {
      const int r = wc * 32 + n * 16 + l15;
      braw[n] = *(const uint4*)(lb + 8192 + r * 64 + lq);
      bscl[n] = *(const f32x2*)(lb + 13312 + r * 8);
    }
    bf16x8 a0[4], a1[4], b0[2], b1[2];
#pragma unroll
    for (int m = 0; m < 4; ++m) {
      a0[m] = dq8(araw[m].x, araw[m].y, ascl[m][0]);
      a1[m] = dq8(araw[m].z, araw[m].w, ascl[m][1]);
    }
#pragma unroll
    for (int n = 0; n < 2; ++n) {
      b0[n] = dq8(braw[n].x, braw[n].y, bscl[n][0]);
      b1[n] = dq8(braw[n].z, braw[n].w, bscl[n][1]);
    }
#pragma unroll
    for (int m = 0; m < 4; ++m)
#pragma unroll
      for (int n = 0; n < 2; ++n) {
        acc[m][n] = __builtin_amdgcn_mfma_f32_16x16x32_bf16(a0[m], b0[n], acc[m][n], 0, 0, 0);
        acc[m][n] = __builtin_amdgcn_mfma_f32_16x16x32_bf16(a1[m], b1[n], acc[m][n], 0, 0, 0);
      }
  };

  STAGE(0, 0);
#pragma unroll 1
  for (int t = 0; t < 30; t += 2) {
    STAGE(1, t + 1);
    WAIT5_BAR();          // tile t's loads done; t+1's stay in flight
    compute(0);
    POST_BAR();           // all waves done reading buf0 before next overwrite
    STAGE(0, t + 2);
    WAIT5_BAR();
    compute(1);
    POST_BAR();
  }
  STAGE(1, 31);
  WAIT5_BAR();
  compute(0);             // tile 30
  POST_BAR();
  asm volatile("s_waitcnt vmcnt(0)" ::: "memory");
  __builtin_amdgcn_sched_barrier(0);
  __builtin_amdgcn_s_barrier();
  compute(1);             // tile 31

  // epilogue: C/D layout col=lane&15, row=(lane>>4)*4+reg  [m89 verified]
  const int rb = row0 + wr * 64 + (lane >> 4) * 4;
#pragma unroll
  for (int n = 0; n < 2; ++n) {
    const int j = col0 + wc * 32 + n * 16 + l15;
    const float bv = bias[j];
#pragma unroll
    for (int m = 0; m < 4; ++m)
#pragma unroll
      for (int r = 0; r < 4; ++r)
        C[(size_t)(rb + m * 16 + r) * NMAT + j] = acc[m][n][r] + bv;
  }
#undef STAGE
#undef WAIT5_BAR
#undef POST_BAR
}

extern "C" void kernel_launch(void* const* d_in, const int* in_sizes, int n_in,
                              void* d_out, int out_size, void* d_ws, size_t ws_size,
                              hipStream_t stream) {
  const float* x  = (const float*)d_in[0];
  const float* w  = (const float*)d_in[1];
  const float* bs = (const float*)d_in[2];
  float* out = (float*)d_out;

  unsigned char* xq = (unsigned char*)d_ws;          // 4MB fp8 x (permuted k)
  unsigned char* wq = xq + 4u * 1024 * 1024;         // 4MB fp8 w
  float* xs  = (float*)(xq + 8u * 1024 * 1024);      // 512KB x scales [2048][64]
  float* wss = xs + 2048 * 64;                       // 512KB w scales

  qdq_kernel<<<dim3(8192), dim3(256), 0, stream>>>(x, xq, xs, w, wq, wss);

  gemm_kernel<<<dim3(512), dim3(256), 0, stream>>>(xq, xs, wq, wss, bs, out);
}

// Round 11
// 115.108 us; speedup vs baseline: 1.1898x; 1.1898x over previous
//
#include <hip/hip_runtime.h>
#include <hip/hip_bf16.h>

// MXFP8Linear: out[n,j] = sum_b sx[n,b]*sw[j,b]*dot32(fp8(x),fp8(w)) + bias[j]
// R10/R11: native fp8 MFMA. mfma_f32_16x16x32_fp8_fp8 has K=32 == one scale
// block, so compute raw block-dot p = mfma(a,b,0) and apply
// acc += (sx*sw)*p on the f32 output — algorithmically identical to the
// reference (exact fp8 products, f32 block dots, f32 scale+sum). No per-
// element dequant VALU (R9's 49% VALUBusy), no bf16 conversion.
// fp8 global layout (written by qdq, staged linearly, read with XOR):
//   byte in 2048B row: g*64 + (q ^ ((row>>1)&3))*16 + kk*8 + j
//   (g=k>>6, q=(k>>3)&3, kk=(k>>5)&1, j=k&7)
// -> one 16B read gives both K-halves of a lane's MFMA operand, and the
// 16B-slot XOR spreads 16 rows over 16 dword-banks x2 = conflict-free.
// Scales stored transposed [block][row] so sx loads are one b128 per (m,kk).

typedef __attribute__((ext_vector_type(4))) float f32x4;
typedef __attribute__((ext_vector_type(2))) unsigned long long u64x2;

#define NMAT 2048
#define FP8_MAX 448.0f

// Coalesced qdq -> fp8 (permuted+swizzled k layout) + [block][row] f32 scales.
__global__ __launch_bounds__(256) void qdq_kernel(const float* __restrict__ x,
                                                  unsigned char* __restrict__ xq,
                                                  float* __restrict__ xs,
                                                  const float* __restrict__ w,
                                                  unsigned char* __restrict__ wq,
                                                  float* __restrict__ wss) {
  int g = blockIdx.x;
  const float* in; unsigned char* oq; float* os;
  if (g >= 4096) { in = w; oq = wq; os = wss; g -= 4096; }
  else           { in = x; oq = xq; os = xs; }
  const int t = threadIdx.x;
  const size_t base = (size_t)g * 1024;  // floats per workgroup
  float4 v = ((const float4*)(in + base))[t];
  float amax = fmaxf(fmaxf(fabsf(v.x), fabsf(v.y)), fmaxf(fabsf(v.z), fabsf(v.w)));
  amax = fmaxf(amax, __shfl_xor(amax, 1));
  amax = fmaxf(amax, __shfl_xor(amax, 2));
  amax = fmaxf(amax, __shfl_xor(amax, 4));
  float s = fmaxf(amax / FP8_MAX, 1e-30f);  // real div to match reference
  int p = __builtin_amdgcn_cvt_pk_fp8_f32(v.x / s, v.y / s, 0, false);
  p = __builtin_amdgcn_cvt_pk_fp8_f32(v.z / s, v.w / s, p, true);
  const int idx = (int)base + t * 4;       // element index
  const int row = idx >> 11;
  const int k   = idx & 2047;
  const int q   = (k >> 3) & 3;
  const int kk  = (k >> 5) & 1;
  const int slot = q ^ ((row >> 1) & 3);   // bank swizzle (involution)
  const int pb  = (k & ~63) | (slot << 4) | (kk << 3) | (k & 7);
  *(unsigned*)(oq + (size_t)row * 2048 + pb) = (unsigned)p;
  if ((t & 7) == 0) os[(k >> 5) * NMAT + row] = s;  // [block][row]
}

// C[n,j] = sum_k A[n,k]*B[j,k] + bias[j]
// BM=128 BN=64 BK=64, 256 thr (4 waves 2Mx2N, wave tile 64x32).
// LDS buf: A fp8 8K | B fp8 4K | Asc [kk][128] 1K | Bsc [dup][kk][64] 1K
//  = 14336 B; double-buffered = 28672 B. grid 512 = 2 blocks/CU.
// Loop: STAGE(next: 5 loads); vmcnt(5); s_barrier; compute(cur); s_barrier.
__global__ __launch_bounds__(256) void gemm_kernel(const unsigned char* __restrict__ Aq,
                                                   const float* __restrict__ As,
                                                   const unsigned char* __restrict__ Bq,
                                                   const float* __restrict__ Bs,
                                                   const float* __restrict__ bias,
                                                   float* __restrict__ C) {
  __shared__ __align__(16) char lds[28672];
  const int tid  = threadIdx.x;
  const int lane = tid & 63;
  const int wid  = tid >> 6;
  const int wr   = wid >> 1;   // 0..1 -> row offset wr*64
  const int wc   = wid & 1;    // 0..1 -> col offset wc*32

  // 2D-chunked XCD mapping (kept from R7; harmless if dispatch differs)
  const int bid = blockIdx.x;
  const int xcd = bid & 7;
  const int k8  = bid >> 3;
  const int row0 = ((xcd >> 2) * 8 + (k8 >> 3)) * 128;
  const int col0 = ((xcd & 3) * 8 + (k8 & 7)) * 64;

  // staging source bases (kt-invariant parts)
  const unsigned char* AgD0 = Aq + (size_t)(row0 + (tid >> 2)) * 2048 + (tid & 3) * 16;
  const unsigned char* AgD1 = Aq + (size_t)(row0 + 64 + (tid >> 2)) * 2048 + (tid & 3) * 16;
  const unsigned char* BgD  = Bq + (size_t)(col0 + (tid >> 2)) * 2048 + (tid & 3) * 16;
  const float* AgS = As + (size_t)(tid >> 7) * NMAT + row0 + (tid & 127);
  const float* BgS = Bs + (size_t)((tid >> 6) & 1) * NMAT + col0 + (tid & 63);
  const int dst16 = tid * 16;
  const int dst4  = tid * 4;

#define STAGE(buf, kt) do {                                                      \
    char* lb = lds + (buf) * 14336;                                              \
    __builtin_amdgcn_global_load_lds(                                            \
        (const __attribute__((address_space(1))) unsigned*)(AgD0 + (kt) * 64),   \
        (__attribute__((address_space(3))) unsigned*)(lb + dst16), 16, 0, 0);    \
    __builtin_amdgcn_global_load_lds(                                            \
        (const __attribute__((address_space(1))) unsigned*)(AgD1 + (kt) * 64),   \
        (__attribute__((address_space(3))) unsigned*)(lb + 4096 + dst16), 16, 0, 0); \
    __builtin_amdgcn_global_load_lds(                                            \
        (const __attribute__((address_space(1))) unsigned*)(BgD + (kt) * 64),    \
        (__attribute__((address_space(3))) unsigned*)(lb + 8192 + dst16), 16, 0, 0); \
    __builtin_amdgcn_global_load_lds(                                            \
        (const __attribute__((address_space(1))) unsigned*)(AgS + (kt) * 2 * NMAT), \
        (__attribute__((address_space(3))) unsigned*)(lb + 12288 + dst4), 4, 0, 0);  \
    __builtin_amdgcn_global_load_lds(                                            \
        (const __attribute__((address_space(1))) unsigned*)(BgS + (kt) * 2 * NMAT), \
        (__attribute__((address_space(3))) unsigned*)(lb + 13312 + dst4), 4, 0, 0);  \
  } while (0)

#define WAIT5_BAR() do {                                   \
    asm volatile("s_waitcnt vmcnt(5)" ::: "memory");       \
    __builtin_amdgcn_sched_barrier(0);                     \
    __builtin_amdgcn_s_barrier();                          \
  } while (0)
#define POST_BAR() do {                                    \
    __builtin_amdgcn_sched_barrier(0);                     \
    __builtin_amdgcn_s_barrier();                          \
  } while (0)

  const int l15  = lane & 15;
  const int q    = lane >> 4;                 // k-octet of this lane
  const int slot = (q ^ ((l15 >> 1) & 3)) * 16;  // swizzled 16B slot in 64B row

  f32x4 acc[4][2] = {};

  auto compute = [&](const int buf) {
    const char* lb = lds + buf * 14336;
    u64x2 araw[4]; f32x4 asc[4][2];
    u64x2 braw[2]; float  bsc[2][2];
#pragma unroll
    for (int m = 0; m < 4; ++m) {
      const int r = wr * 64 + m * 16 + l15;
      araw[m] = *(const u64x2*)(lb + r * 64 + slot);
      const int sr = (wr * 64 + m * 16 + q * 4) * 4;
      asc[m][0] = *(const f32x4*)(lb + 12288 + sr);
      asc[m][1] = *(const f32x4*)(lb + 12288 + 512 + sr);
    }
#pragma unroll
    for (int n = 0; n < 2; ++n) {
      const int r = wc * 32 + n * 16 + l15;
      braw[n] = *(const u64x2*)(lb + 8192 + r * 64 + slot);
      const int sc = (wc * 32 + n * 16 + l15) * 4;
      bsc[n][0] = *(const float*)(lb + 13312 + sc);
      bsc[n][1] = *(const float*)(lb + 13312 + 256 + sc);
    }
    const f32x4 z = {0.f, 0.f, 0.f, 0.f};
#pragma unroll
    for (int m = 0; m < 4; ++m)
#pragma unroll
      for (int n = 0; n < 2; ++n) {
        f32x4 p0 = __builtin_amdgcn_mfma_f32_16x16x32_fp8_fp8(
            (long)araw[m][0], (long)braw[n][0], z, 0, 0, 0);
        acc[m][n] += (asc[m][0] * bsc[n][0]) * p0;
        f32x4 p1 = __builtin_amdgcn_mfma_f32_16x16x32_fp8_fp8(
            (long)araw[m][1], (long)braw[n][1], z, 0, 0, 0);
        acc[m][n] += (asc[m][1] * bsc[n][1]) * p1;
      }
  };

  STAGE(0, 0);
#pragma unroll 1
  for (int t = 0; t < 30; t += 2) {
    STAGE(1, t + 1);
    WAIT5_BAR();          // tile t's loads done; t+1's stay in flight
    compute(0);
    POST_BAR();           // all waves done reading buf0 before next overwrite
    STAGE(0, t + 2);
    WAIT5_BAR();
    compute(1);
    POST_BAR();
  }
  STAGE(1, 31);
  WAIT5_BAR();
  compute(0);             // tile 30
  POST_BAR();
  asm volatile("s_waitcnt vmcnt(0)" ::: "memory");
  __builtin_amdgcn_sched_barrier(0);
  __builtin_amdgcn_s_barrier();
  compute(1);             // tile 31

  // epilogue: C/D layout col=lane&15, row=(lane>>4)*4+reg (dtype-independent)
  const int rb = row0 + wr * 64 + (lane >> 4) * 4;
#pragma unroll
  for (int n = 0; n < 2; ++n) {
    const int j = col0 + wc * 32 + n * 16 + l15;
    const float bv = bias[j];
#pragma unroll
    for (int m = 0; m < 4; ++m)
#pragma unroll
      for (int r = 0; r < 4; ++r)
        C[(size_t)(rb + m * 16 + r) * NMAT + j] = acc[m][n][r] + bv;
  }
#undef STAGE
#undef WAIT5_BAR
#undef POST_BAR
}

extern "C" void kernel_launch(void* const* d_in, const int* in_sizes, int n_in,
                              void* d_out, int out_size, void* d_ws, size_t ws_size,
                              hipStream_t stream) {
  const float* x  = (const float*)d_in[0];
  const float* w  = (const float*)d_in[1];
  const float* bs = (const float*)d_in[2];
  float* out = (float*)d_out;

  unsigned char* xq = (unsigned char*)d_ws;          // 4MB fp8 x (perm+swz)
  unsigned char* wq = xq + 4u * 1024 * 1024;         // 4MB fp8 w
  float* xs  = (float*)(xq + 8u * 1024 * 1024);      // 512KB x scales [blk][row]
  float* wss = xs + 64 * NMAT;                       // 512KB w scales

  qdq_kernel<<<dim3(8192), dim3(256), 0, stream>>>(x, xq, xs, w, wq, wss);

  gemm_kernel<<<dim3(512), dim3(256), 0, stream>>>(xq, xs, wq, wss, bs, out);
}